// Round 1
// baseline (114.200 us; speedup 1.0000x reference)
//
#include <hip/hip_runtime.h>

typedef _Float16 f16;
typedef __attribute__((ext_vector_type(8))) _Float16 f16x8;
typedef __attribute__((ext_vector_type(4))) float f32x4;

#define NSEQ 16
#define QL   128
#define NH   8
#define NG   4
#define DH   128
#define PGSZ 64
#define PPS  16
#define KT   32      // kv tile
#define QIB  32      // query indices per block
#define NQT  (QL / QIB)
#define NWAVE 8
#define KPAD 8       // pad K rows: stride 272B (16B-aligned, 4-bank rotate -> ~2-way)
#define VPAD 8       // pad VT/P rows: stride 80B (16B-aligned, 20-bank rotate -> ~2-way)

__global__ __launch_bounds__(512)
void rpa_fwd(const float* __restrict__ q,
             const float* __restrict__ kv_pages,
             const int* __restrict__ kv_lens,
             const int* __restrict__ page_indices,
             float* __restrict__ out)
{
    const int tid  = threadIdx.x;
    const int wave = tid >> 6;
    const int lane = tid & 63;
    const int c16  = lane & 15;   // lane-in-group (N/col index of fragments)
    const int g16  = lane >> 4;   // 16-lane group id (0..3)

    const int qt = blockIdx.x;    // 0..3
    const int h  = blockIdx.y;    // 0..7
    const int s  = blockIdx.z;    // 0..15

    const int kv_len = kv_lens[s];
    const int kv_end = kv_len - QL + qt*QIB + QIB;   // exclusive kv bound for this block
    // D-fragment rows: row = g16*4 + r  ->  qi = qt*QIB + wave*4 + g16 (lane-uniform over r), g = r
    const int qi_d  = qt*QIB + wave*4 + g16;
    const int q_pos = kv_len - QL + qi_d;

    __shared__ f16 Klds [KT][DH + KPAD];
    __shared__ f16 VTlds[DH][KT + VPAD];
    __shared__ f16 Plds [NWAVE][16][KT + VPAD];

    // ---- Q fragments (A-layout): row = c16, k(d) = sl*32 + g16*8 + j. Pre-scaled.
    f16x8 qfrag[4];
    {
        const int rowA = c16;
        const int qiA  = qt*QIB + wave*4 + (rowA >> 2);
        const int gA   = rowA & 3;
        const int tA   = s*QL + qiA;
        const float* qp = q + (((size_t)tA*NH + h)*NG + gA)*DH;
        const float sc = 0.08838834764831845f;  // 1/sqrt(128)
        #pragma unroll
        for (int sl = 0; sl < 4; ++sl) {
            const float* p = qp + sl*32 + g16*8;
            f32x4 a = *(const f32x4*)p;
            f32x4 b = *(const f32x4*)(p + 4);
            f16x8 f;
            f[0]=(f16)(a[0]*sc); f[1]=(f16)(a[1]*sc); f[2]=(f16)(a[2]*sc); f[3]=(f16)(a[3]*sc);
            f[4]=(f16)(b[0]*sc); f[5]=(f16)(b[1]*sc); f[6]=(f16)(b[2]*sc); f[7]=(f16)(b[3]*sc);
            qfrag[sl] = f;
        }
    }

    f32x4 oacc[8];
    #pragma unroll
    for (int f = 0; f < 8; ++f) oacc[f] = f32x4{0.f, 0.f, 0.f, 0.f};
    float mrun[4] = {-1e30f, -1e30f, -1e30f, -1e30f};
    float lrun[4] = {0.f, 0.f, 0.f, 0.f};

    const int ntile = (kv_end + KT - 1) / KT;
    for (int tile = 0; tile < ntile; ++tile) {
        const int kv0 = tile * KT;

        // ---- stage K tile -> Klds[kv][d] (f16), zero-fill OOB rows
        {
            const int krow = tid >> 4;          // 0..31
            const int d0   = (tid & 15) * 8;    // 0..120
            const int kvp  = kv0 + krow;
            f16x8 kk = {0,0,0,0,0,0,0,0};
            if (kvp < kv_end) {
                const int page = page_indices[s*PPS + (kvp >> 6)];
                const float* kp = kv_pages +
                    ((((size_t)page*PGSZ) + (kvp & (PGSZ-1)))*(2*NH) + h)*DH + d0;
                f32x4 a = *(const f32x4*)kp;
                f32x4 b = *(const f32x4*)(kp + 4);
                kk[0]=(f16)a[0]; kk[1]=(f16)a[1]; kk[2]=(f16)a[2]; kk[3]=(f16)a[3];
                kk[4]=(f16)b[0]; kk[5]=(f16)b[1]; kk[6]=(f16)b[2]; kk[7]=(f16)b[3];
            }
            *(f16x8*)&Klds[krow][d0] = kk;
        }
        // ---- stage V tile transposed -> VTlds[d][kv] (f16), zero-fill OOB
        {
            const int kp2 = tid & 15;           // kv pair index -> kv = 2*kp2, 2*kp2+1
            const int d0  = (tid >> 4) * 4;     // 0..124
            const int kva = kv0 + 2*kp2;
            const int kvb = kva + 1;
            f32x4 va = {0.f,0.f,0.f,0.f}, vb = {0.f,0.f,0.f,0.f};
            if (kva < kv_end) {
                const int page = page_indices[s*PPS + (kva >> 6)];
                va = *(const f32x4*)(kv_pages +
                    ((((size_t)page*PGSZ) + (kva & (PGSZ-1)))*(2*NH) + NH + h)*DH + d0);
            }
            if (kvb < kv_end) {
                const int page = page_indices[s*PPS + (kvb >> 6)];
                vb = *(const f32x4*)(kv_pages +
                    ((((size_t)page*PGSZ) + (kvb & (PGSZ-1)))*(2*NH) + NH + h)*DH + d0);
            }
            #pragma unroll
            for (int j = 0; j < 4; ++j) {
                union { f16 hh[2]; unsigned u; } pk;
                pk.hh[0] = (f16)va[j];
                pk.hh[1] = (f16)vb[j];
                *(unsigned*)&VTlds[d0 + j][2*kp2] = pk.u;
            }
        }
        __syncthreads();

        // ---- QK^T: S[16 rows][32 kv], A=Q, B=K^T (B-frag = contiguous row-slice of Klds)
        f32x4 sacc[2];
        sacc[0] = f32x4{0.f,0.f,0.f,0.f};
        sacc[1] = f32x4{0.f,0.f,0.f,0.f};
        #pragma unroll
        for (int ks = 0; ks < 2; ++ks) {
            #pragma unroll
            for (int sl = 0; sl < 4; ++sl) {
                f16x8 kf = *(const f16x8*)&Klds[ks*16 + c16][sl*32 + g16*8];
                sacc[ks] = __builtin_amdgcn_mfma_f32_16x16x32_f16(qfrag[sl], kf, sacc[ks], 0, 0, 0);
            }
        }

        // ---- online softmax; r indexes the query-group g; mask is lane-uniform over r
        const bool va0 = (kv0 + c16)      <= q_pos;
        const bool va1 = (kv0 + 16 + c16) <= q_pos;
        #pragma unroll
        for (int r = 0; r < 4; ++r) {
            float s0 = va0 ? sacc[0][r] : -1e30f;
            float s1 = va1 ? sacc[1][r] : -1e30f;
            float mt = fmaxf(s0, s1);
            #pragma unroll
            for (int off = 1; off < 16; off <<= 1)
                mt = fmaxf(mt, __shfl_xor(mt, off));
            const float mn  = fmaxf(mrun[r], mt);
            const float fac = __expf(mrun[r] - mn);
            const float p0  = va0 ? __expf(sacc[0][r] - mn) : 0.f;
            const float p1  = va1 ? __expf(sacc[1][r] - mn) : 0.f;
            float rs = p0 + p1;
            #pragma unroll
            for (int off = 1; off < 16; off <<= 1)
                rs += __shfl_xor(rs, off);
            lrun[r] = lrun[r]*fac + rs;
            mrun[r] = mn;
            #pragma unroll
            for (int f = 0; f < 8; ++f) oacc[f][r] *= fac;
            Plds[wave][g16*4 + r][c16]      = (f16)p0;
            Plds[wave][g16*4 + r][16 + c16] = (f16)p1;
        }
        __syncthreads();   // P visible wave-wide; K/VT reads done before restage

        // ---- P @ V: A-frag = contiguous Plds row-slice, B-frag = contiguous VTlds row-slice
        f16x8 pf = *(const f16x8*)&Plds[wave][c16][g16*8];
        #pragma unroll
        for (int f = 0; f < 8; ++f) {
            f16x8 vf = *(const f16x8*)&VTlds[f*16 + c16][g16*8];
            oacc[f] = __builtin_amdgcn_mfma_f32_16x16x32_f16(pf, vf, oacc[f], 0, 0, 0);
        }
        __syncthreads();   // VTlds/Klds consumed before next stage overwrites
    }

    // ---- epilogue: O /= max(l, 1e-10); row = g16*4+r -> (qi_d, g=r)
    const int tD = s*QL + qi_d;
    #pragma unroll
    for (int r = 0; r < 4; ++r) {
        const float inv = 1.f / fmaxf(lrun[r], 1e-10f);
        float* op = out + (((size_t)tD*NH + h)*NG + r)*DH;
        #pragma unroll
        for (int f = 0; f < 8; ++f)
            op[f*16 + c16] = oacc[f][r] * inv;
    }
}

extern "C" void kernel_launch(void* const* d_in, const int* in_sizes, int n_in,
                              void* d_out, int out_size, void* d_ws, size_t ws_size,
                              hipStream_t stream) {
    (void)in_sizes; (void)n_in; (void)d_ws; (void)ws_size; (void)out_size;
    const float* q         = (const float*)d_in[0];
    const float* kv_pages  = (const float*)d_in[1];
    const int*   kv_lens   = (const int*)d_in[2];
    const int*   page_idx  = (const int*)d_in[3];
    // d_in[4] = cu_q_lens (unused), d_in[5] = num_seqs (fixed = 16)
    float* out = (float*)d_out;

    dim3 grid(NQT, NH, NSEQ);   // (4, 8, 16) = 512 blocks
    rpa_fwd<<<grid, 512, 0, stream>>>(q, kv_pages, kv_lens, page_idx, out);
}

// Round 2
// 100.745 us; speedup vs baseline: 1.1336x; 1.1336x over previous
//
#include <hip/hip_runtime.h>

typedef _Float16 f16;
typedef __attribute__((ext_vector_type(8))) _Float16 f16x8;
typedef __attribute__((ext_vector_type(4))) float f32x4;

#define NSEQ 16
#define QL   128
#define NH   8
#define NG   4
#define DH   128
#define PGSZ 64
#define PPS  16
#define KT   32      // kv tile
#define QIB  32      // query indices per block
#define NQT  (QL / QIB)
#define NWAVE 8
#define KPAD 8       // K row stride 272B -> banks rotate by 4, 2-way max (free)
#define VPAD 8       // VT/P row stride 80B -> banks rotate by 20, 2-way max (free)

__global__ __launch_bounds__(512)
void rpa_fwd(const float* __restrict__ q,
             const float* __restrict__ kv_pages,
             const int* __restrict__ kv_lens,
             const int* __restrict__ page_indices,
             float* __restrict__ out)
{
    const int tid  = threadIdx.x;
    const int wave = tid >> 6;
    const int lane = tid & 63;
    const int c16  = lane & 15;   // lane-in-group (N/col index of fragments)
    const int g16  = lane >> 4;   // 16-lane group id (0..3)

    const int qt = blockIdx.x;    // 0..3
    const int h  = blockIdx.y;    // 0..7
    const int s  = blockIdx.z;    // 0..15

    const int kv_len = kv_lens[s];
    const int kv_end = kv_len - QL + qt*QIB + QIB;   // exclusive kv bound for this block
    // D-fragment rows: row = g16*4 + r  ->  qi = qt*QIB + wave*4 + g16, g = r
    const int qi_d  = qt*QIB + wave*4 + g16;
    const int q_pos = kv_len - QL + qi_d;

    __shared__ f16 Klds [2][KT][DH + KPAD];
    __shared__ f16 VTlds[2][DH][KT + VPAD];
    __shared__ f16 Plds [NWAVE][16][KT + VPAD];

    // staging thread mapping (whole block cooperates)
    const int krow = tid >> 4;          // 0..31  (kv row for K)
    const int kd0  = (tid & 15) * 8;    // 0..120 (d offset for K, 8 elems)
    const int vkp2 = tid & 15;          // kv pair index for V -> kv = 2*vkp2, +1
    const int vd0  = (tid >> 4) * 4;    // 0..124 (d offset for V, 4 elems)

    // ---- Q fragments (A-layout): row = c16, k(d) = sl*32 + g16*8 + j. Pre-scaled.
    f16x8 qfrag[4];
    {
        const int rowA = c16;
        const int qiA  = qt*QIB + wave*4 + (rowA >> 2);
        const int gA   = rowA & 3;
        const int tA   = s*QL + qiA;
        const float* qp = q + (((size_t)tA*NH + h)*NG + gA)*DH;
        const float sc = 0.08838834764831845f;  // 1/sqrt(128)
        #pragma unroll
        for (int sl = 0; sl < 4; ++sl) {
            const float* p = qp + sl*32 + g16*8;
            f32x4 a = *(const f32x4*)p;
            f32x4 b = *(const f32x4*)(p + 4);
            f16x8 f;
            f[0]=(f16)(a[0]*sc); f[1]=(f16)(a[1]*sc); f[2]=(f16)(a[2]*sc); f[3]=(f16)(a[3]*sc);
            f[4]=(f16)(b[0]*sc); f[5]=(f16)(b[1]*sc); f[6]=(f16)(b[2]*sc); f[7]=(f16)(b[3]*sc);
            qfrag[sl] = f;
        }
    }

    f32x4 oacc[8];
    #pragma unroll
    for (int f = 0; f < 8; ++f) oacc[f] = f32x4{0.f, 0.f, 0.f, 0.f};
    float mrun[4] = {-1e30f, -1e30f, -1e30f, -1e30f};
    float lrun[4] = {0.f, 0.f, 0.f, 0.f};

    // prefetch registers (tile t+1 in flight while computing tile t)
    f32x4 ka, kb, va, vb;

#define LOAD_TILE(KV0) do {                                                              \
        ka = f32x4{0.f,0.f,0.f,0.f}; kb = ka; va = ka; vb = ka;                          \
        const int kvp_ = (KV0) + krow;                                                   \
        if (kvp_ < kv_end) {                                                             \
            const int pg_ = page_indices[s*PPS + (kvp_ >> 6)];                           \
            const float* kp_ = kv_pages +                                                \
                ((((size_t)pg_*PGSZ) + (kvp_ & (PGSZ-1)))*(2*NH) + h)*DH + kd0;          \
            ka = *(const f32x4*)kp_; kb = *(const f32x4*)(kp_ + 4);                      \
        }                                                                                \
        const int kva_ = (KV0) + 2*vkp2;                                                 \
        if (kva_ < kv_end) {                                                             \
            const int pg_ = page_indices[s*PPS + (kva_ >> 6)];                           \
            va = *(const f32x4*)(kv_pages +                                              \
                ((((size_t)pg_*PGSZ) + (kva_ & (PGSZ-1)))*(2*NH) + NH + h)*DH + vd0);    \
        }                                                                                \
        const int kvb_ = (KV0) + 2*vkp2 + 1;                                             \
        if (kvb_ < kv_end) {                                                             \
            const int pg_ = page_indices[s*PPS + (kvb_ >> 6)];                           \
            vb = *(const f32x4*)(kv_pages +                                              \
                ((((size_t)pg_*PGSZ) + (kvb_ & (PGSZ-1)))*(2*NH) + NH + h)*DH + vd0);    \
        }                                                                                \
    } while (0)

#define WRITE_TILE(BUF) do {                                                             \
        f16x8 kk_;                                                                       \
        kk_[0]=(f16)ka[0]; kk_[1]=(f16)ka[1]; kk_[2]=(f16)ka[2]; kk_[3]=(f16)ka[3];      \
        kk_[4]=(f16)kb[0]; kk_[5]=(f16)kb[1]; kk_[6]=(f16)kb[2]; kk_[7]=(f16)kb[3];      \
        *(f16x8*)&Klds[BUF][krow][kd0] = kk_;                                            \
        _Pragma("unroll")                                                                \
        for (int j_ = 0; j_ < 4; ++j_) {                                                 \
            union { f16 hh[2]; unsigned u; } pk_;                                        \
            pk_.hh[0] = (f16)va[j_];                                                     \
            pk_.hh[1] = (f16)vb[j_];                                                     \
            *(unsigned*)&VTlds[BUF][vd0 + j_][2*vkp2] = pk_.u;                           \
        }                                                                                \
    } while (0)

    const int ntile = (kv_end + KT - 1) / KT;
    LOAD_TILE(0);
    int buf = 0;

    for (int tile = 0; tile < ntile; ++tile) {
        const int kv0 = tile * KT;

        // drain prefetch regs into LDS[buf], then issue next tile's loads
        WRITE_TILE(buf);
        if (tile + 1 < ntile) LOAD_TILE(kv0 + KT);
        __syncthreads();   // single barrier per tile (2-buffer ping-pong is safe)

        // ---- QK^T: S[16 rows][32 kv]
        f32x4 sacc[2];
        sacc[0] = f32x4{0.f,0.f,0.f,0.f};
        sacc[1] = f32x4{0.f,0.f,0.f,0.f};
        #pragma unroll
        for (int ks = 0; ks < 2; ++ks) {
            #pragma unroll
            for (int sl = 0; sl < 4; ++sl) {
                f16x8 kf = *(const f16x8*)&Klds[buf][ks*16 + c16][sl*32 + g16*8];
                sacc[ks] = __builtin_amdgcn_mfma_f32_16x16x32_f16(qfrag[sl], kf, sacc[ks], 0, 0, 0);
            }
        }

        // ---- online softmax; r indexes the query-group g; mask lane-uniform over r
        const bool va0 = (kv0 + c16)      <= q_pos;
        const bool va1 = (kv0 + 16 + c16) <= q_pos;
        #pragma unroll
        for (int r = 0; r < 4; ++r) {
            float s0 = va0 ? sacc[0][r] : -1e30f;
            float s1 = va1 ? sacc[1][r] : -1e30f;
            float mt = fmaxf(s0, s1);
            #pragma unroll
            for (int off = 1; off < 16; off <<= 1)
                mt = fmaxf(mt, __shfl_xor(mt, off));
            const float mn  = fmaxf(mrun[r], mt);
            const float fac = __expf(mrun[r] - mn);
            const float p0  = va0 ? __expf(sacc[0][r] - mn) : 0.f;
            const float p1  = va1 ? __expf(sacc[1][r] - mn) : 0.f;
            float rs = p0 + p1;
            #pragma unroll
            for (int off = 1; off < 16; off <<= 1)
                rs += __shfl_xor(rs, off);
            lrun[r] = lrun[r]*fac + rs;
            mrun[r] = mn;
            #pragma unroll
            for (int f = 0; f < 8; ++f) oacc[f][r] *= fac;
            Plds[wave][g16*4 + r][c16]      = (f16)p0;
            Plds[wave][g16*4 + r][16 + c16] = (f16)p1;
        }
        // NOTE: no barrier — Plds[wave] is wave-private; compiler orders via lgkmcnt

        // ---- P @ V
        f16x8 pf = *(const f16x8*)&Plds[wave][c16][g16*8];
        #pragma unroll
        for (int f = 0; f < 8; ++f) {
            f16x8 vf = *(const f16x8*)&VTlds[buf][f*16 + c16][g16*8];
            oacc[f] = __builtin_amdgcn_mfma_f32_16x16x32_f16(pf, vf, oacc[f], 0, 0, 0);
        }
        buf ^= 1;
        // no trailing barrier: next iteration writes the other buffer, and the
        // iteration-(t+1) barrier fences reads(t) vs writes(t+2) to this buffer
    }

    // ---- epilogue: O /= max(l, 1e-10); row = g16*4+r -> (qi_d, g=r)
    const int tD = s*QL + qi_d;
    #pragma unroll
    for (int r = 0; r < 4; ++r) {
        const float inv = 1.f / fmaxf(lrun[r], 1e-10f);
        float* op = out + (((size_t)tD*NH + h)*NG + r)*DH;
        #pragma unroll
        for (int f = 0; f < 8; ++f)
            op[f*16 + c16] = oacc[f][r] * inv;
    }
}

extern "C" void kernel_launch(void* const* d_in, const int* in_sizes, int n_in,
                              void* d_out, int out_size, void* d_ws, size_t ws_size,
                              hipStream_t stream) {
    (void)in_sizes; (void)n_in; (void)d_ws; (void)ws_size; (void)out_size;
    const float* q         = (const float*)d_in[0];
    const float* kv_pages  = (const float*)d_in[1];
    const int*   kv_lens   = (const int*)d_in[2];
    const int*   page_idx  = (const int*)d_in[3];
    float* out = (float*)d_out;

    dim3 grid(NQT, NH, NSEQ);   // (4, 8, 16) = 512 blocks
    rpa_fwd<<<grid, 512, 0, stream>>>(q, kv_pages, kv_lens, page_idx, out);
}